// Round 2
// baseline (3892.336 us; speedup 1.0000x reference)
//
#include <hip/hip_runtime.h>

// MRI adjoint: masked centered 2D IFFT per (coil,frame) -> conj(smaps) combine
// -> bilinear warp-adjoint scatter -> sum over frames.
// Nx=Ny=320, Nc=16, Nt=25.
//
// FFT: 320 = 5*64. One wave per 1D transform: lane l holds x[5l+q], q=0..4.
// 6-stage radix-2 DIF across lanes (shfl_xor), output index k1 = rev6(lane),
// then per-lane twiddled radix-5: X[k1+64*k2].
// Centered transform: out[n] = (-1)^n * IFFT[ (-1)^k x[k] ] (N=320 even,
// global phase 1). Signs folded into loads/stores. Ortho scale 1/320 folded
// into pass1 input.
// tmp layout [cg][t][y][s] with s = lane + 64*k2 (bit-rev-permuted x rows);
// pass2 maps s -> nx = rev6(s&63) + (s&~63) analytically.
// Layouts: kT[c][y][x], mp[c][y][x] (pass1 reads along x);
//          sT[c][x][y]  (pass2 reads srow[ny] for fixed nx)  <-- round-2 fix
//          fT[t][x][y].

#define NX 320
#define NT 25
#define NC 16
static const float INV320 = 1.0f / 320.0f;

__device__ __forceinline__ int rev6(int l) {
  return ((l & 1) << 5) | ((l & 2) << 3) | ((l & 4) << 1) |
         ((l & 8) >> 1) | ((l & 16) >> 3) | ((l & 32) >> 5);
}

// In-place inverse 320-pt DFT (unnormalized): lane l enters with x[5l+q] in
// re[q],im[q]; exits with X[rev6(l) + 64*q].
__device__ __forceinline__ void fft320(float re[5], float im[5], int lane) {
#pragma unroll
  for (int st = 0; st < 6; ++st) {
    int m = 32 >> st;
    int j = lane & (m - 1);
    float ang = 3.14159265358979323846f * (float)j / (float)m;  // 2*pi*j/(2m)
    float s, c;
    __sincosf(ang, &s, &c);
    bool bot = (lane & m) != 0;
#pragma unroll
    for (int q = 0; q < 5; ++q) {
      float orr = __shfl_xor(re[q], m);
      float oii = __shfl_xor(im[q], m);
      float sr = re[q] + orr, si = im[q] + oii;
      float dr = orr - re[q], di = oii - im[q];
      float tr = dr * c - di * s;
      float ti = dr * s + di * c;
      re[q] = bot ? tr : sr;
      im[q] = bot ? ti : si;
    }
  }
  int k1 = rev6(lane);
  float b = (6.283185307179586f / 320.0f) * (float)k1;
  float s1, c1;
  __sincosf(b, &s1, &c1);
  float c2 = c1 * c1 - s1 * s1, s2 = 2.f * c1 * s1;
  float c3 = c2 * c1 - s2 * s1, s3 = c2 * s1 + s2 * c1;
  float c4 = c2 * c2 - s2 * s2, s4 = 2.f * c2 * s2;
  float t0r = re[0], t0i = im[0];
  float t1r = re[1] * c1 - im[1] * s1, t1i = re[1] * s1 + im[1] * c1;
  float t2r = re[2] * c2 - im[2] * s2, t2i = re[2] * s2 + im[2] * c2;
  float t3r = re[3] * c3 - im[3] * s3, t3i = re[3] * s3 + im[3] * c3;
  float t4r = re[4] * c4 - im[4] * s4, t4i = re[4] * s4 + im[4] * c4;
  const float C1 = 0.30901699437494742f, S1 = 0.95105651629515357f;
  const float C2 = -0.80901699437494742f, S2 = 0.58778525229247312f;
  float a1r = t1r + t4r, a1i = t1i + t4i;
  float b1r = t1r - t4r, b1i = t1i - t4i;
  float a2r = t2r + t3r, a2i = t2i + t3i;
  float b2r = t2r - t3r, b2i = t2i - t3i;
  re[0] = t0r + a1r + a2r;
  im[0] = t0i + a1i + a2i;
  float pr = t0r + C1 * a1r + C2 * a2r, pi = t0i + C1 * a1i + C2 * a2i;
  float qr = S1 * b1r + S2 * b2r, qi = S1 * b1i + S2 * b2i;
  float rr = t0r + C2 * a1r + C1 * a2r, ri = t0i + C2 * a1i + C1 * a2i;
  float ur = S2 * b1r - S1 * b2r, ui = S2 * b1i - S1 * b2i;
  re[1] = pr - qi; im[1] = pi + qr;
  re[4] = pr + qi; im[4] = pi - qr;
  re[2] = rr - ui; im[2] = ri + ur;
  re[3] = rr + ui; im[3] = ri - ur;
}

// mask [x][y][c][t] f32 -> bit-packed mp[c][y][x] (bit t set iff mask!=0)
__global__ __launch_bounds__(256) void pack_mask_k(
    const float* __restrict__ mask, unsigned int* __restrict__ mp) {
  int xt = blockIdx.x, y = blockIdx.y, tid = threadIdx.x;
  int xx = tid >> 4, c = tid & 15;
  int x = xt * 16 + xx;
  const float* src = mask + (size_t)(x * NX + y) * (NC * NT) + c * NT;
  unsigned int bits = 0;
#pragma unroll
  for (int t = 0; t < NT; ++t) bits |= (src[t] != 0.f) ? (1u << t) : 0u;
  __shared__ unsigned int tile[16][17];
  tile[xx][c] = bits;
  __syncthreads();
  int c2 = tid >> 4, xx2 = tid & 15;
  mp[((size_t)(c2 * NX + y)) * NX + xt * 16 + xx2] = tile[xx2][c2];
}

// (ar,ai) [x][y][c] -> dst[c][y][x] float2   (for kspace)
__global__ __launch_bounds__(256) void tr_cplx_k(
    const float* __restrict__ ar, const float* __restrict__ ai,
    float2* __restrict__ dst) {
  int xt = blockIdx.x, y = blockIdx.y, tid = threadIdx.x;
  int xx = tid >> 4, c = tid & 15;
  size_t si = (size_t)((xt * 16 + xx) * NX + y) * NC + c;
  __shared__ float2 tile[16][17];
  tile[xx][c] = make_float2(ar[si], ai[si]);
  __syncthreads();
  int c2 = tid >> 4, xx2 = tid & 15;
  dst[((size_t)(c2 * NX + y)) * NX + xt * 16 + xx2] = tile[xx2][c2];
}

// (ar,ai) [x][y][c] -> dst[c][x][y] float2   (for smaps; pass2 wants [c][nx][ny])
__global__ __launch_bounds__(256) void tr_cplx_cxy_k(
    const float* __restrict__ ar, const float* __restrict__ ai,
    float2* __restrict__ dst) {
  int yt = blockIdx.x, x = blockIdx.y, tid = threadIdx.x;
  int yy = tid >> 4, c = tid & 15;
  size_t si = (size_t)(x * NX + yt * 16 + yy) * NC + c;
  __shared__ float2 tile[16][17];
  tile[yy][c] = make_float2(ar[si], ai[si]);
  __syncthreads();
  int c2 = tid >> 4, yy2 = tid & 15;
  dst[((size_t)(c2 * NX + x)) * NX + yt * 16 + yy2] = tile[yy2][c2];
}

// flow [nx][ny][2][t] -> fT[t][nx][ny] float2 (u,v)
__global__ __launch_bounds__(256) void tr_flow_k(
    const float* __restrict__ fl, float2* __restrict__ dst) {
  int nyt = blockIdx.x, nx = blockIdx.y, tid = threadIdx.x;
  __shared__ float buf[1600];  // 32 ny * 2 d * 25 t
  size_t base = (size_t)(nx * NX + nyt * 32) * (2 * NT);
  for (int f = tid; f < 1600; f += 256) buf[f] = fl[base + f];
  __syncthreads();
  for (int f = tid; f < 1600; f += 256) {
    int t = f / 64;
    int k = f % 64;
    int nyl = k >> 1, d = k & 1;
    size_t di = ((size_t)(t * NX + nx) * NX + nyt * 32 + nyl) * 2 + d;
    ((float*)dst)[di] = buf[(nyl * 2 + d) * NT + t];
  }
}

// Pass 1: x-axis IFFT. One block per (y, coil-in-chunk); wave w does frames
// t = w, w+4, ... Writes tmp[cg][t][y][s], s lane-contiguous.
__global__ __launch_bounds__(256) void pass1_k(
    const float2* __restrict__ kT, const unsigned int* __restrict__ mp,
    float2* __restrict__ tmp, int c0) {
  int y = blockIdx.x, cg = blockIdx.y, c = c0 + cg;
  int tid = threadIdx.x, lane = tid & 63, w = tid >> 6;
  float vr[5], vi[5];
  unsigned int mb[5];
  size_t rowbase = ((size_t)c * NX + y) * NX;
#pragma unroll
  for (int q = 0; q < 5; ++q) {
    int x = 5 * lane + q;
    float2 kv = kT[rowbase + x];
    float sg = ((lane + q) & 1) ? -INV320 : INV320;  // (-1)^x / 320
    vr[q] = kv.x * sg;
    vi[q] = kv.y * sg;
    mb[q] = mp[rowbase + x];
  }
  float osg = (lane & 32) ? -1.f : 1.f;  // (-1)^nx, nx = rev6(lane)+64k2
  for (int t = w; t < NT; t += 4) {
    float ar[5], ai[5];
#pragma unroll
    for (int q = 0; q < 5; ++q) {
      float m = ((mb[q] >> t) & 1u) ? 1.f : 0.f;
      ar[q] = vr[q] * m;
      ai[q] = vi[q] * m;
    }
    fft320(ar, ai, lane);
    float2* dst = tmp + ((size_t)(cg * NT + t) * NX + y) * NX;
#pragma unroll
    for (int k2 = 0; k2 < 5; ++k2)
      dst[lane + 64 * k2] = make_float2(ar[k2] * osg, ai[k2] * osg);
  }
}

// Pass 2: y-axis IFFT + conj(smaps) combine + warp-adjoint scatter.
// Block (s-tile of 16, t), 16 waves; wave j owns stored row s = stile*16+j.
__global__ __launch_bounds__(1024) void pass2_k(
    const float2* __restrict__ tmp, const float2* __restrict__ sT,
    const float2* __restrict__ fT, float* __restrict__ out, int c0, int G) {
  int stile = blockIdx.x, t = blockIdx.y;
  int tid = threadIdx.x, lane = tid & 63, j = tid >> 6;
  int s = stile * 16 + j;
  int nx = rev6(s & 63) + (s & ~63);
  int k1 = rev6(lane);
  __shared__ float2 tile[NX][17];
  float accr[5] = {0, 0, 0, 0, 0}, acci[5] = {0, 0, 0, 0, 0};
  for (int cg = 0; cg < G; ++cg) {
    __syncthreads();
    const float2* src = tmp + ((size_t)(cg * NT + t) * NX) * NX + stile * 16;
#pragma unroll
    for (int q = 0; q < 5; ++q) {
      int f = tid + q * 1024;
      int y = f >> 4, jj = f & 15;
      tile[y][jj] = src[(size_t)y * NX + jj];
    }
    __syncthreads();
    float ar[5], ai[5];
#pragma unroll
    for (int q = 0; q < 5; ++q) {
      float2 v = tile[5 * lane + q][j];
      float sg = ((lane + q) & 1) ? -1.f : 1.f;  // (-1)^y
      ar[q] = v.x * sg;
      ai[q] = v.y * sg;
    }
    fft320(ar, ai, lane);
    const float2* srow = sT + ((size_t)(c0 + cg) * NX + nx) * NX;
#pragma unroll
    for (int k2 = 0; k2 < 5; ++k2) {
      int ny = k1 + 64 * k2;
      float2 sm = srow[ny];
      accr[k2] += ar[k2] * sm.x + ai[k2] * sm.y;  // X * conj(S)
      acci[k2] += ai[k2] * sm.x - ar[k2] * sm.y;
    }
  }
  float osg = (lane & 32) ? -1.f : 1.f;  // (-1)^ny
  const float2* frow = fT + ((size_t)t * NX + nx) * NX;
#pragma unroll
  for (int k2 = 0; k2 < 5; ++k2) {
    int ny = k1 + 64 * k2;
    float vr = accr[k2] * osg, vi = acci[k2] * osg;
    float2 fl = frow[ny];
    float px = fminf(fmaxf((float)nx + fl.x, 0.f), 319.f);
    float py = fminf(fmaxf((float)ny + fl.y, 0.f), 319.f);
    int x0 = (int)floorf(px), y0 = (int)floorf(py);
    int x1 = min(x0 + 1, NX - 1), y1 = min(y0 + 1, NX - 1);
    float wx = px - (float)x0, wy = py - (float)y0;
    float w00 = (1.f - wx) * (1.f - wy), w01 = (1.f - wx) * wy;
    float w10 = wx * (1.f - wy), w11 = wx * wy;
    float* o00 = out + (size_t)(x0 * NX + y0) * 2;
    float* o01 = out + (size_t)(x0 * NX + y1) * 2;
    float* o10 = out + (size_t)(x1 * NX + y0) * 2;
    float* o11 = out + (size_t)(x1 * NX + y1) * 2;
    atomicAdd(o00, vr * w00);
    atomicAdd(o00 + 1, vi * w00);
    atomicAdd(o01, vr * w01);
    atomicAdd(o01 + 1, vi * w01);
    atomicAdd(o10, vr * w10);
    atomicAdd(o10 + 1, vi * w10);
    atomicAdd(o11, vr * w11);
    atomicAdd(o11 + 1, vi * w11);
  }
}

extern "C" void kernel_launch(void* const* d_in, const int* in_sizes, int n_in,
                              void* d_out, int out_size, void* d_ws,
                              size_t ws_size, hipStream_t stream) {
  const float* kr = (const float*)d_in[0];
  const float* ki = (const float*)d_in[1];
  const float* mask = (const float*)d_in[2];
  const float* sr = (const float*)d_in[3];
  const float* si = (const float*)d_in[4];
  const float* fl = (const float*)d_in[5];
  float* out = (float*)d_out;

  const size_t perCoil = (size_t)NT * NX * NX * 8;       // 20.48 MB
  const size_t kT_b = (size_t)NC * NX * NX * 8;          // 13.1 MB
  const size_t sT_b = kT_b;
  const size_t fT_b = (size_t)NT * NX * NX * 8;          // 20.48 MB
  const size_t mp_b = (size_t)NC * NX * NX * 4;          // 6.55 MB
  const size_t fixedB = kT_b + sT_b + fT_b + mp_b;

  int G = 1;
  if (ws_size >= fixedB + 4 * perCoil) G = 4;
  else if (ws_size >= fixedB + 2 * perCoil) G = 2;

  char* w = (char*)d_ws;
  float2* tmp = (float2*)w;            w += (size_t)G * perCoil;
  float2* kT = (float2*)w;             w += kT_b;
  float2* sT = (float2*)w;             w += sT_b;
  float2* fT = (float2*)w;             w += fT_b;
  unsigned int* mp = (unsigned int*)w;

  hipMemsetAsync(d_out, 0, (size_t)NX * NX * 2 * sizeof(float), stream);

  pack_mask_k<<<dim3(NX / 16, NX), 256, 0, stream>>>(mask, mp);
  tr_cplx_k<<<dim3(NX / 16, NX), 256, 0, stream>>>(kr, ki, kT);
  tr_cplx_cxy_k<<<dim3(NX / 16, NX), 256, 0, stream>>>(sr, si, sT);
  tr_flow_k<<<dim3(NX / 32, NX), 256, 0, stream>>>(fl, fT);

  for (int c0 = 0; c0 < NC; c0 += G) {
    pass1_k<<<dim3(NX, G), 256, 0, stream>>>(kT, mp, tmp, c0);
    pass2_k<<<dim3(NX / 16, NT), 1024, 0, stream>>>(tmp, sT, fT, out, c0, G);
  }
}

// Round 3
// 502.122 us; speedup vs baseline: 7.7518x; 7.7518x over previous
//
#include <hip/hip_runtime.h>

// MRI adjoint: masked centered 2D IFFT per (coil,frame) -> conj(smaps) combine
// -> bilinear warp-adjoint scatter -> sum over frames.
// Nx=Ny=320, Nc=16, Nt=25.
//
// FFT: 320 = 5*64. One wave per 1D transform: lane l holds x[5l+q], q=0..4.
// 6-stage radix-2 DIF across lanes (shfl_xor), output index k1 = rev6(lane),
// then per-lane twiddled radix-5: X[k1+64*k2].
// Centered transform: out[n] = (-1)^n * IFFT[ (-1)^k x[k] ] (N=320 even).
// Storage order: column s holds spatial index perm(s)=rev6(s&63)+(s&~63)
// (self-inverse). im_aux[t][nx][s], fs[t][nx][s] both s-ordered so the
// scatter kernel reads coalesced and computes ny=perm(s) arithmetically.
//
// Scatter (round-3 rewrite): NO global atomics. Output split into 10 row
// bands of 32; block (band,t) accumulates its band in LDS (80KB) from source
// rows [r0-32, r0+64), LDS atomics, writes band to out_t[t]. Contributions
// with |target_row - src_row| beyond the window (essentially never: flow is
// 3*N(0,1)) spill to a zeroed out_f via rare global atomics. reduce_k sums
// out_f + sum_t out_t.

#define NX 320
#define NT 25
#define NC 16
#define BR 32  // scatter band rows
#define WH 32  // scatter read-window halfwidth
static const float INV320 = 1.0f / 320.0f;

__device__ __forceinline__ int rev6(int l) {
  return ((l & 1) << 5) | ((l & 2) << 3) | ((l & 4) << 1) |
         ((l & 8) >> 1) | ((l & 16) >> 3) | ((l & 32) >> 5);
}

// In-place inverse 320-pt DFT (unnormalized): lane l enters with x[5l+q] in
// re[q],im[q]; exits with X[rev6(l) + 64*q].
__device__ __forceinline__ void fft320(float re[5], float im[5], int lane) {
#pragma unroll
  for (int st = 0; st < 6; ++st) {
    int m = 32 >> st;
    int j = lane & (m - 1);
    float ang = 3.14159265358979323846f * (float)j / (float)m;
    float s, c;
    __sincosf(ang, &s, &c);
    bool bot = (lane & m) != 0;
#pragma unroll
    for (int q = 0; q < 5; ++q) {
      float orr = __shfl_xor(re[q], m);
      float oii = __shfl_xor(im[q], m);
      float sr = re[q] + orr, si = im[q] + oii;
      float dr = orr - re[q], di = oii - im[q];
      float tr = dr * c - di * s;
      float ti = dr * s + di * c;
      re[q] = bot ? tr : sr;
      im[q] = bot ? ti : si;
    }
  }
  int k1 = rev6(lane);
  float b = (6.283185307179586f / 320.0f) * (float)k1;
  float s1, c1;
  __sincosf(b, &s1, &c1);
  float c2 = c1 * c1 - s1 * s1, s2 = 2.f * c1 * s1;
  float c3 = c2 * c1 - s2 * s1, s3 = c2 * s1 + s2 * c1;
  float c4 = c2 * c2 - s2 * s2, s4 = 2.f * c2 * s2;
  float t0r = re[0], t0i = im[0];
  float t1r = re[1] * c1 - im[1] * s1, t1i = re[1] * s1 + im[1] * c1;
  float t2r = re[2] * c2 - im[2] * s2, t2i = re[2] * s2 + im[2] * c2;
  float t3r = re[3] * c3 - im[3] * s3, t3i = re[3] * s3 + im[3] * c3;
  float t4r = re[4] * c4 - im[4] * s4, t4i = re[4] * s4 + im[4] * c4;
  const float C1 = 0.30901699437494742f, S1 = 0.95105651629515357f;
  const float C2 = -0.80901699437494742f, S2 = 0.58778525229247312f;
  float a1r = t1r + t4r, a1i = t1i + t4i;
  float b1r = t1r - t4r, b1i = t1i - t4i;
  float a2r = t2r + t3r, a2i = t2i + t3i;
  float b2r = t2r - t3r, b2i = t2i - t3i;
  re[0] = t0r + a1r + a2r;
  im[0] = t0i + a1i + a2i;
  float pr = t0r + C1 * a1r + C2 * a2r, pi = t0i + C1 * a1i + C2 * a2i;
  float qr = S1 * b1r + S2 * b2r, qi = S1 * b1i + S2 * b2i;
  float rr = t0r + C2 * a1r + C1 * a2r, ri = t0i + C2 * a1i + C1 * a2i;
  float ur = S2 * b1r - S1 * b2r, ui = S2 * b1i - S1 * b2i;
  re[1] = pr - qi; im[1] = pi + qr;
  re[4] = pr + qi; im[4] = pi - qr;
  re[2] = rr - ui; im[2] = ri + ur;
  re[3] = rr + ui; im[3] = ri - ur;
}

// mask [x][y][c][t] f32 -> bit-packed mp[c][y][x] (bit t set iff mask!=0)
__global__ __launch_bounds__(256) void pack_mask_k(
    const float* __restrict__ mask, unsigned int* __restrict__ mp) {
  int xt = blockIdx.x, y = blockIdx.y, tid = threadIdx.x;
  int xx = tid >> 4, c = tid & 15;
  int x = xt * 16 + xx;
  const float* src = mask + (size_t)(x * NX + y) * (NC * NT) + c * NT;
  unsigned int bits = 0;
#pragma unroll
  for (int t = 0; t < NT; ++t) bits |= (src[t] != 0.f) ? (1u << t) : 0u;
  __shared__ unsigned int tile[16][17];
  tile[xx][c] = bits;
  __syncthreads();
  int c2 = tid >> 4, xx2 = tid & 15;
  mp[((size_t)(c2 * NX + y)) * NX + xt * 16 + xx2] = tile[xx2][c2];
}

// (ar,ai) [x][y][c] -> dst[c][y][x] float2   (for kspace)
__global__ __launch_bounds__(256) void tr_cplx_k(
    const float* __restrict__ ar, const float* __restrict__ ai,
    float2* __restrict__ dst) {
  int xt = blockIdx.x, y = blockIdx.y, tid = threadIdx.x;
  int xx = tid >> 4, c = tid & 15;
  size_t si = (size_t)((xt * 16 + xx) * NX + y) * NC + c;
  __shared__ float2 tile[16][17];
  tile[xx][c] = make_float2(ar[si], ai[si]);
  __syncthreads();
  int c2 = tid >> 4, xx2 = tid & 15;
  dst[((size_t)(c2 * NX + y)) * NX + xt * 16 + xx2] = tile[xx2][c2];
}

// (ar,ai) [x][y][c] -> dst[c][x][y] float2   (for smaps)
__global__ __launch_bounds__(256) void tr_cplx_cxy_k(
    const float* __restrict__ ar, const float* __restrict__ ai,
    float2* __restrict__ dst) {
  int yt = blockIdx.x, x = blockIdx.y, tid = threadIdx.x;
  int yy = tid >> 4, c = tid & 15;
  size_t si = (size_t)(x * NX + yt * 16 + yy) * NC + c;
  __shared__ float2 tile[16][17];
  tile[yy][c] = make_float2(ar[si], ai[si]);
  __syncthreads();
  int c2 = tid >> 4, yy2 = tid & 15;
  dst[((size_t)(c2 * NX + x)) * NX + yt * 16 + yy2] = tile[yy2][c2];
}

// flow [nx][ny][2][t] -> fs[t][nx][s] float2 with s-order columns
__global__ __launch_bounds__(256) void tr_flow_k(
    const float* __restrict__ fl, float2* __restrict__ dst) {
  int nyt = blockIdx.x, nx = blockIdx.y, tid = threadIdx.x;
  __shared__ float buf[1600];  // 32 ny * 2 d * 25 t
  size_t base = (size_t)(nx * NX + nyt * 32) * (2 * NT);
  for (int f = tid; f < 1600; f += 256) buf[f] = fl[base + f];
  __syncthreads();
  for (int f = tid; f < 1600; f += 256) {
    int t = f / 64;
    int k = f % 64;
    int nyl = k >> 1, d = k & 1;
    int ny = nyt * 32 + nyl;
    int s = rev6(ny & 63) + (ny & ~63);  // store permuted
    size_t di = ((size_t)(t * NX + nx) * NX + s) * 2 + d;
    ((float*)dst)[di] = buf[(nyl * 2 + d) * NT + t];
  }
}

// Pass 1: x-axis IFFT. One block per (y, coil-in-chunk); wave w does frames
// t = w, w+4, ... Writes tmp[cg][t][y][s], s lane-contiguous.
__global__ __launch_bounds__(256) void pass1_k(
    const float2* __restrict__ kT, const unsigned int* __restrict__ mp,
    float2* __restrict__ tmp, int c0) {
  int y = blockIdx.x, cg = blockIdx.y, c = c0 + cg;
  int tid = threadIdx.x, lane = tid & 63, w = tid >> 6;
  float vr[5], vi[5];
  unsigned int mb[5];
  size_t rowbase = ((size_t)c * NX + y) * NX;
#pragma unroll
  for (int q = 0; q < 5; ++q) {
    int x = 5 * lane + q;
    float2 kv = kT[rowbase + x];
    float sg = ((lane + q) & 1) ? -INV320 : INV320;  // (-1)^x / 320
    vr[q] = kv.x * sg;
    vi[q] = kv.y * sg;
    mb[q] = mp[rowbase + x];
  }
  float osg = (lane & 32) ? -1.f : 1.f;  // (-1)^nx, nx = rev6(lane)+64k2
  for (int t = w; t < NT; t += 4) {
    float ar[5], ai[5];
#pragma unroll
    for (int q = 0; q < 5; ++q) {
      float m = ((mb[q] >> t) & 1u) ? 1.f : 0.f;
      ar[q] = vr[q] * m;
      ai[q] = vi[q] * m;
    }
    fft320(ar, ai, lane);
    float2* dst = tmp + ((size_t)(cg * NT + t) * NX + y) * NX;
#pragma unroll
    for (int k2 = 0; k2 < 5; ++k2)
      dst[lane + 64 * k2] = make_float2(ar[k2] * osg, ai[k2] * osg);
  }
}

// Pass 2: y-axis IFFT + conj(smaps) combine -> im_aux[t][nx][s] (s-ordered).
// first=1: write; first=0: accumulate.
__global__ __launch_bounds__(1024) void pass2_k(
    const float2* __restrict__ tmp, const float2* __restrict__ sT,
    float2* __restrict__ im_aux, int c0, int G, int first) {
  int stile = blockIdx.x, t = blockIdx.y;
  int tid = threadIdx.x, lane = tid & 63, j = tid >> 6;
  int s = stile * 16 + j;
  int nx = rev6(s & 63) + (s & ~63);
  int k1 = rev6(lane);
  __shared__ float2 tile[NX][17];
  float accr[5] = {0, 0, 0, 0, 0}, acci[5] = {0, 0, 0, 0, 0};
  for (int cg = 0; cg < G; ++cg) {
    __syncthreads();
    const float2* src = tmp + ((size_t)(cg * NT + t) * NX) * NX + stile * 16;
#pragma unroll
    for (int q = 0; q < 5; ++q) {
      int f = tid + q * 1024;
      int y = f >> 4, jj = f & 15;
      tile[y][jj] = src[(size_t)y * NX + jj];
    }
    __syncthreads();
    float ar[5], ai[5];
#pragma unroll
    for (int q = 0; q < 5; ++q) {
      float2 v = tile[5 * lane + q][j];
      float sg = ((lane + q) & 1) ? -1.f : 1.f;  // (-1)^y
      ar[q] = v.x * sg;
      ai[q] = v.y * sg;
    }
    fft320(ar, ai, lane);
    const float2* srow = sT + ((size_t)(c0 + cg) * NX + nx) * NX;
#pragma unroll
    for (int k2 = 0; k2 < 5; ++k2) {
      int ny = k1 + 64 * k2;
      float2 sm = srow[ny];
      accr[k2] += ar[k2] * sm.x + ai[k2] * sm.y;  // X * conj(S)
      acci[k2] += ai[k2] * sm.x - ar[k2] * sm.y;
    }
  }
  float osg = (lane & 32) ? -1.f : 1.f;  // (-1)^ny
  float2* dst = im_aux + ((size_t)t * NX + nx) * NX;
#pragma unroll
  for (int k2 = 0; k2 < 5; ++k2) {
    int sc = lane + 64 * k2;  // perm(sc) = ny
    float2 nv = make_float2(accr[k2] * osg, acci[k2] * osg);
    if (!first) {
      float2 old = dst[sc];
      nv.x += old.x;
      nv.y += old.y;
    }
    dst[sc] = nv;
  }
}

// Scatter: block (band b, frame t). LDS-privatized 32-row output band.
__global__ __launch_bounds__(1024) void scatter_k(
    const float2* __restrict__ im, const float2* __restrict__ fs,
    float* __restrict__ out_t, float* __restrict__ out_f) {
  int b = blockIdx.x, t = blockIdx.y;
  int r0 = b * BR;
  int tid = threadIdx.x, lane = tid & 63, w = tid >> 6;
  __shared__ float acc[BR * NX * 2];  // 80 KB
  for (int i = tid; i < BR * NX * 2; i += 1024) acc[i] = 0.f;
  __syncthreads();
  int lo = max(r0 - WH, 0), hi = min(r0 + BR + WH, NX);
  for (int nx = lo + w; nx < hi; nx += 16) {
    bool own = (nx >= r0) && (nx < r0 + BR);
    const float2* imrow = im + ((size_t)t * NX + nx) * NX;
    const float2* frow = fs + ((size_t)t * NX + nx) * NX;
#pragma unroll
    for (int q = 0; q < 5; ++q) {
      int s = lane + 64 * q;
      int ny = rev6(s & 63) + (s & ~63);
      float2 v = imrow[s];
      float2 fl = frow[s];
      float px = fminf(fmaxf((float)nx + fl.x, 0.f), 319.f);
      float py = fminf(fmaxf((float)ny + fl.y, 0.f), 319.f);
      int x0 = (int)floorf(px), y0 = (int)floorf(py);
      int x1 = min(x0 + 1, NX - 1), y1 = min(y0 + 1, NX - 1);
      float wx = px - (float)x0, wy = py - (float)y0;
      float w00 = (1.f - wx) * (1.f - wy), w01 = (1.f - wx) * wy;
      float w10 = wx * (1.f - wy), w11 = wx * wy;
#pragma unroll
      for (int half = 0; half < 2; ++half) {
        int r = half ? x1 : x0;
        float wa = half ? w10 : w00;
        float wb = half ? w11 : w01;
        if (r >= r0 && r < r0 + BR) {
          float* p0 = &acc[((r - r0) * NX + y0) * 2];
          float* p1 = &acc[((r - r0) * NX + y1) * 2];
          atomicAdd(p0, wa * v.x);
          atomicAdd(p0 + 1, wa * v.y);
          atomicAdd(p1, wb * v.x);
          atomicAdd(p1 + 1, wb * v.y);
        } else if (own) {
          int rb = (r / BR) * BR;
          if (nx < rb - WH || nx >= rb + BR + WH) {  // no band covers it
            atomicAdd(&out_f[((size_t)r * NX + y0) * 2], wa * v.x);
            atomicAdd(&out_f[((size_t)r * NX + y0) * 2 + 1], wa * v.y);
            atomicAdd(&out_f[((size_t)r * NX + y1) * 2], wb * v.x);
            atomicAdd(&out_f[((size_t)r * NX + y1) * 2 + 1], wb * v.y);
          }
        }
      }
    }
  }
  __syncthreads();
  float* dst = out_t + ((size_t)t * NX * NX + (size_t)r0 * NX) * 2;
  for (int i = tid; i < BR * NX * 2; i += 1024) dst[i] = acc[i];
}

// out = out_f + sum_t out_t  (float4 over 204800 floats)
__global__ __launch_bounds__(256) void reduce_k(
    const float* __restrict__ out_t, const float* __restrict__ out_f,
    float* __restrict__ out) {
  const int n4 = NX * NX * 2 / 4;  // 51200
  int i = blockIdx.x * 256 + threadIdx.x;
  if (i >= n4) return;
  float4 s = ((const float4*)out_f)[i];
  for (int t = 0; t < NT; ++t) {
    float4 v = ((const float4*)out_t)[(size_t)t * n4 + i];
    s.x += v.x; s.y += v.y; s.z += v.z; s.w += v.w;
  }
  ((float4*)out)[i] = s;
}

extern "C" void kernel_launch(void* const* d_in, const int* in_sizes, int n_in,
                              void* d_out, int out_size, void* d_ws,
                              size_t ws_size, hipStream_t stream) {
  const float* kr = (const float*)d_in[0];
  const float* ki = (const float*)d_in[1];
  const float* mask = (const float*)d_in[2];
  const float* sr = (const float*)d_in[3];
  const float* si = (const float*)d_in[4];
  const float* fl = (const float*)d_in[5];
  float* out = (float*)d_out;

  const size_t perCoil = (size_t)NT * NX * NX * 8;   // 20.48 MB
  const size_t kT_b = (size_t)NC * NX * NX * 8;      // 13.1 MB
  const size_t sT_b = kT_b;
  const size_t fs_b = (size_t)NT * NX * NX * 8;      // 20.48 MB
  const size_t mp_b = (size_t)NC * NX * NX * 4;      // 6.55 MB
  const size_t ia_b = (size_t)NT * NX * NX * 8;      // 20.48 MB
  const size_t ot_b = (size_t)NT * NX * NX * 2 * 4;  // 20.48 MB
  const size_t of_b = (size_t)NX * NX * 2 * 4;       // 0.82 MB
  const size_t fixedB = kT_b + sT_b + fs_b + mp_b + ia_b + ot_b + of_b;

  int G = 1;
  if (ws_size >= fixedB + 4 * perCoil) G = 4;
  else if (ws_size >= fixedB + 2 * perCoil) G = 2;

  char* w = (char*)d_ws;
  float2* tmp = (float2*)w;      w += (size_t)G * perCoil;
  float2* kT = (float2*)w;       w += kT_b;
  float2* sT = (float2*)w;       w += sT_b;
  float2* fs = (float2*)w;       w += fs_b;
  float2* im_aux = (float2*)w;   w += ia_b;
  float* out_t = (float*)w;      w += ot_b;
  float* out_f = (float*)w;      w += of_b;
  unsigned int* mp = (unsigned int*)w;

  pack_mask_k<<<dim3(NX / 16, NX), 256, 0, stream>>>(mask, mp);
  tr_cplx_k<<<dim3(NX / 16, NX), 256, 0, stream>>>(kr, ki, kT);
  tr_cplx_cxy_k<<<dim3(NX / 16, NX), 256, 0, stream>>>(sr, si, sT);
  tr_flow_k<<<dim3(NX / 32, NX), 256, 0, stream>>>(fl, fs);
  hipMemsetAsync(out_f, 0, of_b, stream);

  for (int c0 = 0; c0 < NC; c0 += G) {
    pass1_k<<<dim3(NX, G), 256, 0, stream>>>(kT, mp, tmp, c0);
    pass2_k<<<dim3(NX / 16, NT), 1024, 0, stream>>>(tmp, sT, im_aux, c0, G,
                                                    c0 == 0 ? 1 : 0);
  }
  scatter_k<<<dim3(NX / BR, NT), 1024, 0, stream>>>(im_aux, fs, out_t, out_f);
  reduce_k<<<200, 256, 0, stream>>>(out_t, out_f, out);
}

// Round 4
// 496.704 us; speedup vs baseline: 7.8363x; 1.0109x over previous
//
#include <hip/hip_runtime.h>
#include <hip/hip_fp16.h>

// MRI adjoint: masked centered 2D IFFT per (coil,frame) -> conj(smaps) combine
// -> bilinear warp-adjoint scatter -> sum over frames. Nx=Ny=320, Nc=16, Nt=25.
//
// FFT: 320 = 5*64; one wave per transform (6-stage radix-2 across lanes via
// shfl_xor + per-lane twiddled radix-5). Centered: out[n]=(-1)^n IFFT[(-1)^k x].
// Twiddles hoisted (pure function of lane) - no sincos in the hot loop.
// tmp (x-IFFT result) stored fp16 (half2), NATURAL x order: pass1 writes at
// nx = rev6(lane)+64*k2 (permuted-dense 512B groups coalesce same as linear).
// im_aux, fs natural order too -> scatter reads are linear.
// Scatter: 10 row-bands x NSEG source-segments x 25 frames; LDS-privatized
// 32x320 band accumulator; out-of-window targets (essentially never: flow is
// 3*N(0,1)) spill to zeroed out_f via global atomics. reduce sums all slices.

#define NX 320
#define NT 25
#define NC 16
#define BR 32
#define WH 32
static const float INV320 = 1.0f / 320.0f;

__device__ __forceinline__ int rev6(int l) {
  return ((l & 1) << 5) | ((l & 2) << 3) | ((l & 4) << 1) |
         ((l & 8) >> 1) | ((l & 16) >> 3) | ((l & 32) >> 5);
}

struct Tw {
  float c[6], s[6];
  float c1, s1, c2, s2, c3, s3, c4, s4;
};

__device__ __forceinline__ void make_tw(int lane, Tw& tw) {
#pragma unroll
  for (int st = 0; st < 6; ++st) {
    int m = 32 >> st;
    int j = lane & (m - 1);
    float ang = 3.14159265358979323846f * (float)j / (float)m;
    __sincosf(ang, &tw.s[st], &tw.c[st]);
  }
  int k1 = rev6(lane);
  float b = (6.283185307179586f / 320.0f) * (float)k1;
  __sincosf(b, &tw.s1, &tw.c1);
  tw.c2 = tw.c1 * tw.c1 - tw.s1 * tw.s1;
  tw.s2 = 2.f * tw.c1 * tw.s1;
  tw.c3 = tw.c2 * tw.c1 - tw.s2 * tw.s1;
  tw.s3 = tw.c2 * tw.s1 + tw.s2 * tw.c1;
  tw.c4 = tw.c2 * tw.c2 - tw.s2 * tw.s2;
  tw.s4 = 2.f * tw.c2 * tw.s2;
}

// Unnormalized inverse 320-pt DFT: lane l enters with x[5l+q] in re/im[q];
// exits with X[rev6(l) + 64*q].
__device__ __forceinline__ void fft320(float re[5], float im[5], int lane,
                                       const Tw& tw) {
#pragma unroll
  for (int st = 0; st < 6; ++st) {
    int m = 32 >> st;
    float c = tw.c[st], s = tw.s[st];
    bool bot = (lane & m) != 0;
#pragma unroll
    for (int q = 0; q < 5; ++q) {
      float orr = __shfl_xor(re[q], m);
      float oii = __shfl_xor(im[q], m);
      float sr = re[q] + orr, si = im[q] + oii;
      float dr = orr - re[q], di = oii - im[q];
      float tr = dr * c - di * s;
      float ti = dr * s + di * c;
      re[q] = bot ? tr : sr;
      im[q] = bot ? ti : si;
    }
  }
  float t0r = re[0], t0i = im[0];
  float t1r = re[1] * tw.c1 - im[1] * tw.s1, t1i = re[1] * tw.s1 + im[1] * tw.c1;
  float t2r = re[2] * tw.c2 - im[2] * tw.s2, t2i = re[2] * tw.s2 + im[2] * tw.c2;
  float t3r = re[3] * tw.c3 - im[3] * tw.s3, t3i = re[3] * tw.s3 + im[3] * tw.c3;
  float t4r = re[4] * tw.c4 - im[4] * tw.s4, t4i = re[4] * tw.s4 + im[4] * tw.c4;
  const float C1 = 0.30901699437494742f, S1 = 0.95105651629515357f;
  const float C2 = -0.80901699437494742f, S2 = 0.58778525229247312f;
  float a1r = t1r + t4r, a1i = t1i + t4i;
  float b1r = t1r - t4r, b1i = t1i - t4i;
  float a2r = t2r + t3r, a2i = t2i + t3i;
  float b2r = t2r - t3r, b2i = t2i - t3i;
  re[0] = t0r + a1r + a2r;
  im[0] = t0i + a1i + a2i;
  float pr = t0r + C1 * a1r + C2 * a2r, pi = t0i + C1 * a1i + C2 * a2i;
  float qr = S1 * b1r + S2 * b2r, qi = S1 * b1i + S2 * b2i;
  float rr = t0r + C2 * a1r + C1 * a2r, ri = t0i + C2 * a1i + C1 * a2i;
  float ur = S2 * b1r - S1 * b2r, ui = S2 * b1i - S1 * b2i;
  re[1] = pr - qi; im[1] = pi + qr;
  re[4] = pr + qi; im[4] = pi - qr;
  re[2] = rr - ui; im[2] = ri + ur;
  re[3] = rr + ui; im[3] = ri - ur;
}

// mask [x][y][c][t] f32 -> bit-packed mp[c][y][x]
__global__ __launch_bounds__(256) void pack_mask_k(
    const float* __restrict__ mask, unsigned int* __restrict__ mp) {
  int xt = blockIdx.x, y = blockIdx.y, tid = threadIdx.x;
  int xx = tid >> 4, c = tid & 15;
  int x = xt * 16 + xx;
  const float* src = mask + (size_t)(x * NX + y) * (NC * NT) + c * NT;
  unsigned int bits = 0;
#pragma unroll
  for (int t = 0; t < NT; ++t) bits |= (src[t] != 0.f) ? (1u << t) : 0u;
  __shared__ unsigned int tile[16][17];
  tile[xx][c] = bits;
  __syncthreads();
  int c2 = tid >> 4, xx2 = tid & 15;
  mp[((size_t)(c2 * NX + y)) * NX + xt * 16 + xx2] = tile[xx2][c2];
}

// (ar,ai) [x][y][c] -> dst[c][y][x] float2   (kspace)
__global__ __launch_bounds__(256) void tr_cplx_k(
    const float* __restrict__ ar, const float* __restrict__ ai,
    float2* __restrict__ dst) {
  int xt = blockIdx.x, y = blockIdx.y, tid = threadIdx.x;
  int xx = tid >> 4, c = tid & 15;
  size_t si = (size_t)((xt * 16 + xx) * NX + y) * NC + c;
  __shared__ float2 tile[16][17];
  tile[xx][c] = make_float2(ar[si], ai[si]);
  __syncthreads();
  int c2 = tid >> 4, xx2 = tid & 15;
  dst[((size_t)(c2 * NX + y)) * NX + xt * 16 + xx2] = tile[xx2][c2];
}

// (ar,ai) [x][y][c] -> dst[c][x][y] float2   (smaps)
__global__ __launch_bounds__(256) void tr_cplx_cxy_k(
    const float* __restrict__ ar, const float* __restrict__ ai,
    float2* __restrict__ dst) {
  int yt = blockIdx.x, x = blockIdx.y, tid = threadIdx.x;
  int yy = tid >> 4, c = tid & 15;
  size_t si = (size_t)(x * NX + yt * 16 + yy) * NC + c;
  __shared__ float2 tile[16][17];
  tile[yy][c] = make_float2(ar[si], ai[si]);
  __syncthreads();
  int c2 = tid >> 4, yy2 = tid & 15;
  dst[((size_t)(c2 * NX + x)) * NX + yt * 16 + yy2] = tile[yy2][c2];
}

// flow [nx][ny][2][t] -> fs[t][nx][ny] float2 (natural order)
__global__ __launch_bounds__(256) void tr_flow_k(
    const float* __restrict__ fl, float2* __restrict__ dst) {
  int nyt = blockIdx.x, nx = blockIdx.y, tid = threadIdx.x;
  __shared__ float buf[1600];
  size_t base = (size_t)(nx * NX + nyt * 32) * (2 * NT);
  for (int f = tid; f < 1600; f += 256) buf[f] = fl[base + f];
  __syncthreads();
  for (int f = tid; f < 1600; f += 256) {
    int t = f / 64;
    int k = f % 64;
    int nyl = k >> 1, d = k & 1;
    size_t di = ((size_t)(t * NX + nx) * NX + nyt * 32 + nyl) * 2 + d;
    ((float*)dst)[di] = buf[(nyl * 2 + d) * NT + t];
  }
}

// Pass 1: x-axis IFFT for coil chunk [c0, c0+G). Writes tmp[cg][t][y][nx] fp16.
__global__ __launch_bounds__(256) void pass1_k(
    const float2* __restrict__ kT, const unsigned int* __restrict__ mp,
    __half2* __restrict__ tmp, int c0) {
  int y = blockIdx.x, cg = blockIdx.y, c = c0 + cg;
  int tid = threadIdx.x, lane = tid & 63, w = tid >> 6;
  float vr[5], vi[5];
  unsigned int mb[5];
  size_t rowbase = ((size_t)c * NX + y) * NX;
#pragma unroll
  for (int q = 0; q < 5; ++q) {
    int x = 5 * lane + q;
    float2 kv = kT[rowbase + x];
    float sg = ((lane + q) & 1) ? -INV320 : INV320;  // (-1)^x / 320
    vr[q] = kv.x * sg;
    vi[q] = kv.y * sg;
    mb[q] = mp[rowbase + x];
  }
  Tw tw;
  make_tw(lane, tw);
  int r6 = rev6(lane);
  float osg = (lane & 32) ? -1.f : 1.f;  // (-1)^nx
  for (int t = w; t < NT; t += 4) {
    float ar[5], ai[5];
#pragma unroll
    for (int q = 0; q < 5; ++q) {
      float m = ((mb[q] >> t) & 1u) ? 1.f : 0.f;
      ar[q] = vr[q] * m;
      ai[q] = vi[q] * m;
    }
    fft320(ar, ai, lane, tw);
    __half2* dst = tmp + ((size_t)(cg * NT + t) * NX + y) * NX;
#pragma unroll
    for (int k2 = 0; k2 < 5; ++k2)
      dst[r6 + 64 * k2] = __floats2half2_rn(ar[k2] * osg, ai[k2] * osg);
  }
}

// Pass 2: y-axis IFFT + conj(smaps) combine -> im_aux[t][nx][ny] (natural).
// 512 threads; block = (nx-tile of 8, t). first=1 write, else accumulate.
__global__ __launch_bounds__(512) void pass2_k(
    const __half2* __restrict__ tmp, const float2* __restrict__ sT,
    float2* __restrict__ im_aux, int c0, int G, int first) {
  int nxt = blockIdx.x, t = blockIdx.y;
  int tid = threadIdx.x, lane = tid & 63, j = tid >> 6;
  int nx = nxt * 8 + j;
  int k1 = rev6(lane);
  Tw tw;
  make_tw(lane, tw);
  __shared__ __half2 tile[NX][9];
  float accr[5] = {0, 0, 0, 0, 0}, acci[5] = {0, 0, 0, 0, 0};
  for (int cg = 0; cg < G; ++cg) {
    __syncthreads();
    const __half2* src = tmp + ((size_t)(cg * NT + t) * NX) * NX + nxt * 8;
#pragma unroll
    for (int q = 0; q < 5; ++q) {
      int f = tid + q * 512;
      int y = f >> 3, jj = f & 7;
      tile[y][jj] = src[(size_t)y * NX + jj];
    }
    __syncthreads();
    float ar[5], ai[5];
#pragma unroll
    for (int q = 0; q < 5; ++q) {
      float2 v = __half22float2(tile[5 * lane + q][j]);
      float sg = ((lane + q) & 1) ? -1.f : 1.f;  // (-1)^y
      ar[q] = v.x * sg;
      ai[q] = v.y * sg;
    }
    fft320(ar, ai, lane, tw);
    const float2* srow = sT + ((size_t)(c0 + cg) * NX + nx) * NX;
#pragma unroll
    for (int k2 = 0; k2 < 5; ++k2) {
      int ny = k1 + 64 * k2;
      float2 sm = srow[ny];
      accr[k2] += ar[k2] * sm.x + ai[k2] * sm.y;  // X * conj(S)
      acci[k2] += ai[k2] * sm.x - ar[k2] * sm.y;
    }
  }
  float osg = (lane & 32) ? -1.f : 1.f;  // (-1)^ny
  float2* dst = im_aux + ((size_t)t * NX + nx) * NX;
#pragma unroll
  for (int k2 = 0; k2 < 5; ++k2) {
    int ny = k1 + 64 * k2;
    float2 nv = make_float2(accr[k2] * osg, acci[k2] * osg);
    if (!first) {
      float2 old = dst[ny];
      nv.x += old.x;
      nv.y += old.y;
    }
    dst[ny] = nv;
  }
}

// Scatter: block (band b, seg, frame t). LDS-privatized 32-row band.
__global__ __launch_bounds__(1024) void scatter_k(
    const float2* __restrict__ im, const float2* __restrict__ fs,
    float* __restrict__ out_p, float* __restrict__ out_f, int nseg) {
  int b = blockIdx.x, seg = blockIdx.y, t = blockIdx.z;
  int r0 = b * BR;
  int tid = threadIdx.x, lane = tid & 63, w = tid >> 6;
  __shared__ float acc[BR * NX * 2];  // 80 KB
  for (int i = tid; i < BR * NX * 2; i += 1024) acc[i] = 0.f;
  __syncthreads();
  int lo = max(r0 - WH, 0), hi = min(r0 + BR + WH, NX);
  int stride = 16 * nseg;
  for (int nx = lo + seg * 16 + w; nx < hi; nx += stride) {
    bool own = (nx >= r0) && (nx < r0 + BR);
    const float2* imrow = im + ((size_t)t * NX + nx) * NX;
    const float2* frow = fs + ((size_t)t * NX + nx) * NX;
#pragma unroll
    for (int q = 0; q < 5; ++q) {
      int ny = lane + 64 * q;
      float2 v = imrow[ny];
      float2 fl = frow[ny];
      float px = fminf(fmaxf((float)nx + fl.x, 0.f), 319.f);
      float py = fminf(fmaxf((float)ny + fl.y, 0.f), 319.f);
      int x0 = (int)floorf(px), y0 = (int)floorf(py);
      int x1 = min(x0 + 1, NX - 1), y1 = min(y0 + 1, NX - 1);
      float wx = px - (float)x0, wy = py - (float)y0;
      float w00 = (1.f - wx) * (1.f - wy), w01 = (1.f - wx) * wy;
      float w10 = wx * (1.f - wy), w11 = wx * wy;
#pragma unroll
      for (int half = 0; half < 2; ++half) {
        int r = half ? x1 : x0;
        float wa = half ? w10 : w00;
        float wb = half ? w11 : w01;
        if (r >= r0 && r < r0 + BR) {
          float* p0 = &acc[((r - r0) * NX + y0) * 2];
          float* p1 = &acc[((r - r0) * NX + y1) * 2];
          atomicAdd(p0, wa * v.x);
          atomicAdd(p0 + 1, wa * v.y);
          atomicAdd(p1, wb * v.x);
          atomicAdd(p1 + 1, wb * v.y);
        } else if (own) {
          int rb = (r / BR) * BR;
          if (nx < rb - WH || nx >= rb + BR + WH) {  // no band reads nx
            atomicAdd(&out_f[((size_t)r * NX + y0) * 2], wa * v.x);
            atomicAdd(&out_f[((size_t)r * NX + y0) * 2 + 1], wa * v.y);
            atomicAdd(&out_f[((size_t)r * NX + y1) * 2], wb * v.x);
            atomicAdd(&out_f[((size_t)r * NX + y1) * 2 + 1], wb * v.y);
          }
        }
      }
    }
  }
  __syncthreads();
  float* dst = out_p + ((size_t)(seg * NT + t) * NX + r0) * NX * 2;
  for (int i = tid; i < BR * NX * 2; i += 1024) dst[i] = acc[i];
}

// out = out_f + sum_{seg,t} out_p
__global__ __launch_bounds__(256) void reduce_k(
    const float* __restrict__ out_p, const float* __restrict__ out_f,
    float* __restrict__ out, int nslice) {
  const int n4 = NX * NX * 2 / 4;
  int i = blockIdx.x * 256 + threadIdx.x;
  if (i >= n4) return;
  float4 s = ((const float4*)out_f)[i];
  for (int k = 0; k < nslice; ++k) {
    float4 v = ((const float4*)out_p)[(size_t)k * n4 + i];
    s.x += v.x; s.y += v.y; s.z += v.z; s.w += v.w;
  }
  ((float4*)out)[i] = s;
}

extern "C" void kernel_launch(void* const* d_in, const int* in_sizes, int n_in,
                              void* d_out, int out_size, void* d_ws,
                              size_t ws_size, hipStream_t stream) {
  const float* kr = (const float*)d_in[0];
  const float* ki = (const float*)d_in[1];
  const float* mask = (const float*)d_in[2];
  const float* sr = (const float*)d_in[3];
  const float* si = (const float*)d_in[4];
  const float* fl = (const float*)d_in[5];
  float* out = (float*)d_out;

  const size_t tmp1 = (size_t)NT * NX * NX * 4;      // fp16 complex, per coil
  const size_t kT_b = (size_t)NC * NX * NX * 8;
  const size_t sT_b = kT_b;
  const size_t fs_b = (size_t)NT * NX * NX * 8;
  const size_t mp_b = (size_t)NC * NX * NX * 4;
  const size_t ia_b = (size_t)NT * NX * NX * 8;
  const size_t of_b = (size_t)NX * NX * 8;
  const size_t op1 = (size_t)NT * NX * NX * 8;       // per scatter segment

  int NSEG = 4, G = 16;
  for (;;) {
    size_t fixed = kT_b + sT_b + fs_b + mp_b + ia_b + of_b + NSEG * op1;
    if (ws_size >= fixed + (size_t)G * tmp1) break;
    if (G > 1) { G >>= 1; continue; }
    if (NSEG > 1) { NSEG >>= 1; G = 16; continue; }
    break;  // minimal config; assume it fits
  }

  char* w = (char*)d_ws;
  __half2* tmp = (__half2*)w;   w += (size_t)G * tmp1;
  float2* kT = (float2*)w;      w += kT_b;
  float2* sT = (float2*)w;      w += sT_b;
  float2* fs = (float2*)w;      w += fs_b;
  float2* im_aux = (float2*)w;  w += ia_b;
  float* out_p = (float*)w;     w += (size_t)NSEG * op1;
  float* out_f = (float*)w;     w += of_b;
  unsigned int* mp = (unsigned int*)w;

  pack_mask_k<<<dim3(NX / 16, NX), 256, 0, stream>>>(mask, mp);
  tr_cplx_k<<<dim3(NX / 16, NX), 256, 0, stream>>>(kr, ki, kT);
  tr_cplx_cxy_k<<<dim3(NX / 16, NX), 256, 0, stream>>>(sr, si, sT);
  tr_flow_k<<<dim3(NX / 32, NX), 256, 0, stream>>>(fl, fs);
  hipMemsetAsync(out_f, 0, of_b, stream);

  for (int c0 = 0; c0 < NC; c0 += G) {
    pass1_k<<<dim3(NX, G), 256, 0, stream>>>(kT, mp, tmp, c0);
    pass2_k<<<dim3(NX / 8, NT), 512, 0, stream>>>(tmp, sT, im_aux, c0, G,
                                                  c0 == 0 ? 1 : 0);
  }
  scatter_k<<<dim3(NX / BR, NSEG, NT), 1024, 0, stream>>>(im_aux, fs, out_p,
                                                          out_f, NSEG);
  reduce_k<<<200, 256, 0, stream>>>(out_p, out_f, out, NSEG * NT);
}

// Round 5
// 418.734 us; speedup vs baseline: 9.2955x; 1.1862x over previous
//
#include <hip/hip_runtime.h>
#include <hip/hip_fp16.h>

// MRI adjoint: masked centered 2D IFFT per (coil,frame) -> conj(smaps) combine
// -> bilinear warp-adjoint scatter -> sum over frames. Nx=Ny=320, Nc=16, Nt=25.
//
// FFT: 320 = 5*64; one wave per transform (6-stage radix-2 across lanes via
// shfl_xor + per-lane twiddled radix-5). Centered: out[n]=(-1)^n IFFT[(-1)^k x].
// tmp (x-IFFT result) stored fp16 (half2), natural x order.
// Scatter: 10 row-bands x NSEG source-segments x 25 frames; LDS-privatized
// 32x320 band accumulator via unsafeAtomicAdd (native ds_add_f32 -- plain
// atomicAdd on f32 lowers to a CAS loop on AMD and was the round-2..4
// bottleneck). Out-of-window targets (>5 sigma flow) spill to zeroed out_f.

#define NX 320
#define NT 25
#define NC 16
#define BR 32
#define WH 16
static const float INV320 = 1.0f / 320.0f;

__device__ __forceinline__ int rev6(int l) {
  return ((l & 1) << 5) | ((l & 2) << 3) | ((l & 4) << 1) |
         ((l & 8) >> 1) | ((l & 16) >> 3) | ((l & 32) >> 5);
}

struct Tw {
  float c[6], s[6];
  float c1, s1, c2, s2, c3, s3, c4, s4;
};

__device__ __forceinline__ void make_tw(int lane, Tw& tw) {
#pragma unroll
  for (int st = 0; st < 6; ++st) {
    int m = 32 >> st;
    int j = lane & (m - 1);
    float ang = 3.14159265358979323846f * (float)j / (float)m;
    __sincosf(ang, &tw.s[st], &tw.c[st]);
  }
  int k1 = rev6(lane);
  float b = (6.283185307179586f / 320.0f) * (float)k1;
  __sincosf(b, &tw.s1, &tw.c1);
  tw.c2 = tw.c1 * tw.c1 - tw.s1 * tw.s1;
  tw.s2 = 2.f * tw.c1 * tw.s1;
  tw.c3 = tw.c2 * tw.c1 - tw.s2 * tw.s1;
  tw.s3 = tw.c2 * tw.s1 + tw.s2 * tw.c1;
  tw.c4 = tw.c2 * tw.c2 - tw.s2 * tw.s2;
  tw.s4 = 2.f * tw.c2 * tw.s2;
}

// Unnormalized inverse 320-pt DFT: lane l enters with x[5l+q] in re/im[q];
// exits with X[rev6(l) + 64*q].
__device__ __forceinline__ void fft320(float re[5], float im[5], int lane,
                                       const Tw& tw) {
#pragma unroll
  for (int st = 0; st < 6; ++st) {
    int m = 32 >> st;
    float c = tw.c[st], s = tw.s[st];
    bool bot = (lane & m) != 0;
#pragma unroll
    for (int q = 0; q < 5; ++q) {
      float orr = __shfl_xor(re[q], m);
      float oii = __shfl_xor(im[q], m);
      float sr = re[q] + orr, si = im[q] + oii;
      float dr = orr - re[q], di = oii - im[q];
      float tr = dr * c - di * s;
      float ti = dr * s + di * c;
      re[q] = bot ? tr : sr;
      im[q] = bot ? ti : si;
    }
  }
  float t0r = re[0], t0i = im[0];
  float t1r = re[1] * tw.c1 - im[1] * tw.s1, t1i = re[1] * tw.s1 + im[1] * tw.c1;
  float t2r = re[2] * tw.c2 - im[2] * tw.s2, t2i = re[2] * tw.s2 + im[2] * tw.c2;
  float t3r = re[3] * tw.c3 - im[3] * tw.s3, t3i = re[3] * tw.s3 + im[3] * tw.c3;
  float t4r = re[4] * tw.c4 - im[4] * tw.s4, t4i = re[4] * tw.s4 + im[4] * tw.c4;
  const float C1 = 0.30901699437494742f, S1 = 0.95105651629515357f;
  const float C2 = -0.80901699437494742f, S2 = 0.58778525229247312f;
  float a1r = t1r + t4r, a1i = t1i + t4i;
  float b1r = t1r - t4r, b1i = t1i - t4i;
  float a2r = t2r + t3r, a2i = t2i + t3i;
  float b2r = t2r - t3r, b2i = t2i - t3i;
  re[0] = t0r + a1r + a2r;
  im[0] = t0i + a1i + a2i;
  float pr = t0r + C1 * a1r + C2 * a2r, pi = t0i + C1 * a1i + C2 * a2i;
  float qr = S1 * b1r + S2 * b2r, qi = S1 * b1i + S2 * b2i;
  float rr = t0r + C2 * a1r + C1 * a2r, ri = t0i + C2 * a1i + C1 * a2i;
  float ur = S2 * b1r - S1 * b2r, ui = S2 * b1i - S1 * b2i;
  re[1] = pr - qi; im[1] = pi + qr;
  re[4] = pr + qi; im[4] = pi - qr;
  re[2] = rr - ui; im[2] = ri + ur;
  re[3] = rr + ui; im[3] = ri - ur;
}

// mask [x][y][c][t] f32 -> bit-packed mp[c][y][x]
__global__ __launch_bounds__(256) void pack_mask_k(
    const float* __restrict__ mask, unsigned int* __restrict__ mp) {
  int xt = blockIdx.x, y = blockIdx.y, tid = threadIdx.x;
  int xx = tid >> 4, c = tid & 15;
  int x = xt * 16 + xx;
  const float* src = mask + (size_t)(x * NX + y) * (NC * NT) + c * NT;
  unsigned int bits = 0;
#pragma unroll
  for (int t = 0; t < NT; ++t) bits |= (src[t] != 0.f) ? (1u << t) : 0u;
  __shared__ unsigned int tile[16][17];
  tile[xx][c] = bits;
  __syncthreads();
  int c2 = tid >> 4, xx2 = tid & 15;
  mp[((size_t)(c2 * NX + y)) * NX + xt * 16 + xx2] = tile[xx2][c2];
}

// (ar,ai) [x][y][c] -> dst[c][y][x] float2   (kspace)
__global__ __launch_bounds__(256) void tr_cplx_k(
    const float* __restrict__ ar, const float* __restrict__ ai,
    float2* __restrict__ dst) {
  int xt = blockIdx.x, y = blockIdx.y, tid = threadIdx.x;
  int xx = tid >> 4, c = tid & 15;
  size_t si = (size_t)((xt * 16 + xx) * NX + y) * NC + c;
  __shared__ float2 tile[16][17];
  tile[xx][c] = make_float2(ar[si], ai[si]);
  __syncthreads();
  int c2 = tid >> 4, xx2 = tid & 15;
  dst[((size_t)(c2 * NX + y)) * NX + xt * 16 + xx2] = tile[xx2][c2];
}

// (ar,ai) [x][y][c] -> dst[c][x][y] float2   (smaps)
__global__ __launch_bounds__(256) void tr_cplx_cxy_k(
    const float* __restrict__ ar, const float* __restrict__ ai,
    float2* __restrict__ dst) {
  int yt = blockIdx.x, x = blockIdx.y, tid = threadIdx.x;
  int yy = tid >> 4, c = tid & 15;
  size_t si = (size_t)(x * NX + yt * 16 + yy) * NC + c;
  __shared__ float2 tile[16][17];
  tile[yy][c] = make_float2(ar[si], ai[si]);
  __syncthreads();
  int c2 = tid >> 4, yy2 = tid & 15;
  dst[((size_t)(c2 * NX + x)) * NX + yt * 16 + yy2] = tile[yy2][c2];
}

// flow [nx][ny][2][t] -> fs[t][nx][ny] float2 (natural order)
__global__ __launch_bounds__(256) void tr_flow_k(
    const float* __restrict__ fl, float2* __restrict__ dst) {
  int nyt = blockIdx.x, nx = blockIdx.y, tid = threadIdx.x;
  __shared__ float buf[1600];
  size_t base = (size_t)(nx * NX + nyt * 32) * (2 * NT);
  for (int f = tid; f < 1600; f += 256) buf[f] = fl[base + f];
  __syncthreads();
  for (int f = tid; f < 1600; f += 256) {
    int t = f / 64;
    int k = f % 64;
    int nyl = k >> 1, d = k & 1;
    size_t di = ((size_t)(t * NX + nx) * NX + nyt * 32 + nyl) * 2 + d;
    ((float*)dst)[di] = buf[(nyl * 2 + d) * NT + t];
  }
}

// Pass 1: x-axis IFFT for coil chunk [c0, c0+G). Writes tmp[cg][t][y][nx] fp16.
__global__ __launch_bounds__(256) void pass1_k(
    const float2* __restrict__ kT, const unsigned int* __restrict__ mp,
    __half2* __restrict__ tmp, int c0) {
  int y = blockIdx.x, cg = blockIdx.y, c = c0 + cg;
  int tid = threadIdx.x, lane = tid & 63, w = tid >> 6;
  float vr[5], vi[5];
  unsigned int mb[5];
  size_t rowbase = ((size_t)c * NX + y) * NX;
#pragma unroll
  for (int q = 0; q < 5; ++q) {
    int x = 5 * lane + q;
    float2 kv = kT[rowbase + x];
    float sg = ((lane + q) & 1) ? -INV320 : INV320;  // (-1)^x / 320
    vr[q] = kv.x * sg;
    vi[q] = kv.y * sg;
    mb[q] = mp[rowbase + x];
  }
  Tw tw;
  make_tw(lane, tw);
  int r6 = rev6(lane);
  float osg = (lane & 32) ? -1.f : 1.f;  // (-1)^nx
  for (int t = w; t < NT; t += 4) {
    float ar[5], ai[5];
#pragma unroll
    for (int q = 0; q < 5; ++q) {
      float m = ((mb[q] >> t) & 1u) ? 1.f : 0.f;
      ar[q] = vr[q] * m;
      ai[q] = vi[q] * m;
    }
    fft320(ar, ai, lane, tw);
    __half2* dst = tmp + ((size_t)(cg * NT + t) * NX + y) * NX;
#pragma unroll
    for (int k2 = 0; k2 < 5; ++k2)
      dst[r6 + 64 * k2] = __floats2half2_rn(ar[k2] * osg, ai[k2] * osg);
  }
}

// Pass 2: y-axis IFFT + conj(smaps) combine -> im_aux[t][nx][ny] (natural).
// 512 threads; block = (nx-tile of 8, t). first=1 write, else accumulate.
__global__ __launch_bounds__(512) void pass2_k(
    const __half2* __restrict__ tmp, const float2* __restrict__ sT,
    float2* __restrict__ im_aux, int c0, int G, int first) {
  int nxt = blockIdx.x, t = blockIdx.y;
  int tid = threadIdx.x, lane = tid & 63, j = tid >> 6;
  int nx = nxt * 8 + j;
  int k1 = rev6(lane);
  Tw tw;
  make_tw(lane, tw);
  __shared__ __half2 tile[NX][9];
  float accr[5] = {0, 0, 0, 0, 0}, acci[5] = {0, 0, 0, 0, 0};
  for (int cg = 0; cg < G; ++cg) {
    __syncthreads();
    const __half2* src = tmp + ((size_t)(cg * NT + t) * NX) * NX + nxt * 8;
#pragma unroll
    for (int q = 0; q < 5; ++q) {
      int f = tid + q * 512;
      int y = f >> 3, jj = f & 7;
      tile[y][jj] = src[(size_t)y * NX + jj];
    }
    __syncthreads();
    float ar[5], ai[5];
#pragma unroll
    for (int q = 0; q < 5; ++q) {
      float2 v = __half22float2(tile[5 * lane + q][j]);
      float sg = ((lane + q) & 1) ? -1.f : 1.f;  // (-1)^y
      ar[q] = v.x * sg;
      ai[q] = v.y * sg;
    }
    fft320(ar, ai, lane, tw);
    const float2* srow = sT + ((size_t)(c0 + cg) * NX + nx) * NX;
#pragma unroll
    for (int k2 = 0; k2 < 5; ++k2) {
      int ny = k1 + 64 * k2;
      float2 sm = srow[ny];
      accr[k2] += ar[k2] * sm.x + ai[k2] * sm.y;  // X * conj(S)
      acci[k2] += ai[k2] * sm.x - ar[k2] * sm.y;
    }
  }
  float osg = (lane & 32) ? -1.f : 1.f;  // (-1)^ny
  float2* dst = im_aux + ((size_t)t * NX + nx) * NX;
#pragma unroll
  for (int k2 = 0; k2 < 5; ++k2) {
    int ny = k1 + 64 * k2;
    float2 nv = make_float2(accr[k2] * osg, acci[k2] * osg);
    if (!first) {
      float2 old = dst[ny];
      nv.x += old.x;
      nv.y += old.y;
    }
    dst[ny] = nv;
  }
}

// Scatter: block (band b, seg, frame t). LDS-privatized 32-row band.
__global__ __launch_bounds__(1024) void scatter_k(
    const float2* __restrict__ im, const float2* __restrict__ fs,
    float* __restrict__ out_p, float* __restrict__ out_f, int nseg) {
  int b = blockIdx.x, seg = blockIdx.y, t = blockIdx.z;
  int r0 = b * BR;
  int tid = threadIdx.x, lane = tid & 63, w = tid >> 6;
  __shared__ float acc[BR * NX * 2];  // 80 KB
  for (int i = tid; i < BR * NX * 2; i += 1024) acc[i] = 0.f;
  __syncthreads();
  int lo = max(r0 - WH, 0), hi = min(r0 + BR + WH, NX);
  int stride = 16 * nseg;
  for (int nx = lo + seg * 16 + w; nx < hi; nx += stride) {
    bool own = (nx >= r0) && (nx < r0 + BR);
    const float2* imrow = im + ((size_t)t * NX + nx) * NX;
    const float2* frow = fs + ((size_t)t * NX + nx) * NX;
#pragma unroll
    for (int q = 0; q < 5; ++q) {
      int ny = lane + 64 * q;
      float2 v = imrow[ny];
      float2 fl = frow[ny];
      float px = fminf(fmaxf((float)nx + fl.x, 0.f), 319.f);
      float py = fminf(fmaxf((float)ny + fl.y, 0.f), 319.f);
      int x0 = (int)floorf(px), y0 = (int)floorf(py);
      int x1 = min(x0 + 1, NX - 1), y1 = min(y0 + 1, NX - 1);
      float wx = px - (float)x0, wy = py - (float)y0;
      float w00 = (1.f - wx) * (1.f - wy), w01 = (1.f - wx) * wy;
      float w10 = wx * (1.f - wy), w11 = wx * wy;
#pragma unroll
      for (int half = 0; half < 2; ++half) {
        int r = half ? x1 : x0;
        float wa = half ? w10 : w00;
        float wb = half ? w11 : w01;
        if (r >= r0 && r < r0 + BR) {
          float* p0 = &acc[((r - r0) * NX + y0) * 2];
          float* p1 = &acc[((r - r0) * NX + y1) * 2];
          unsafeAtomicAdd(p0, wa * v.x);
          unsafeAtomicAdd(p0 + 1, wa * v.y);
          unsafeAtomicAdd(p1, wb * v.x);
          unsafeAtomicAdd(p1 + 1, wb * v.y);
        } else if (own) {
          int rb = (r / BR) * BR;
          if (nx < rb - WH || nx >= rb + BR + WH) {  // no band reads nx
            unsafeAtomicAdd(&out_f[((size_t)r * NX + y0) * 2], wa * v.x);
            unsafeAtomicAdd(&out_f[((size_t)r * NX + y0) * 2 + 1], wa * v.y);
            unsafeAtomicAdd(&out_f[((size_t)r * NX + y1) * 2], wb * v.x);
            unsafeAtomicAdd(&out_f[((size_t)r * NX + y1) * 2 + 1], wb * v.y);
          }
        }
      }
    }
  }
  __syncthreads();
  float* dst = out_p + ((size_t)(seg * NT + t) * NX + r0) * NX * 2;
  for (int i = tid; i < BR * NX * 2; i += 1024) dst[i] = acc[i];
}

// out = out_f + sum_{seg,t} out_p
__global__ __launch_bounds__(256) void reduce_k(
    const float* __restrict__ out_p, const float* __restrict__ out_f,
    float* __restrict__ out, int nslice) {
  const int n4 = NX * NX * 2 / 4;
  int i = blockIdx.x * 256 + threadIdx.x;
  if (i >= n4) return;
  float4 s = ((const float4*)out_f)[i];
  for (int k = 0; k < nslice; ++k) {
    float4 v = ((const float4*)out_p)[(size_t)k * n4 + i];
    s.x += v.x; s.y += v.y; s.z += v.z; s.w += v.w;
  }
  ((float4*)out)[i] = s;
}

extern "C" void kernel_launch(void* const* d_in, const int* in_sizes, int n_in,
                              void* d_out, int out_size, void* d_ws,
                              size_t ws_size, hipStream_t stream) {
  const float* kr = (const float*)d_in[0];
  const float* ki = (const float*)d_in[1];
  const float* mask = (const float*)d_in[2];
  const float* sr = (const float*)d_in[3];
  const float* si = (const float*)d_in[4];
  const float* fl = (const float*)d_in[5];
  float* out = (float*)d_out;

  const size_t tmp1 = (size_t)NT * NX * NX * 4;      // fp16 complex, per coil
  const size_t kT_b = (size_t)NC * NX * NX * 8;
  const size_t sT_b = kT_b;
  const size_t fs_b = (size_t)NT * NX * NX * 8;
  const size_t mp_b = (size_t)NC * NX * NX * 4;
  const size_t ia_b = (size_t)NT * NX * NX * 8;
  const size_t of_b = (size_t)NX * NX * 8;
  const size_t op1 = (size_t)NT * NX * NX * 8;       // per scatter segment

  int NSEG = 2, G = 16;
  for (;;) {
    size_t fixed = kT_b + sT_b + fs_b + mp_b + ia_b + of_b + NSEG * op1;
    if (ws_size >= fixed + (size_t)G * tmp1) break;
    if (G > 1) { G >>= 1; continue; }
    if (NSEG > 1) { NSEG >>= 1; G = 16; continue; }
    break;  // minimal config; assume it fits
  }

  char* w = (char*)d_ws;
  __half2* tmp = (__half2*)w;   w += (size_t)G * tmp1;
  float2* kT = (float2*)w;      w += kT_b;
  float2* sT = (float2*)w;      w += sT_b;
  float2* fs = (float2*)w;      w += fs_b;
  float2* im_aux = (float2*)w;  w += ia_b;
  float* out_p = (float*)w;     w += (size_t)NSEG * op1;
  float* out_f = (float*)w;     w += of_b;
  unsigned int* mp = (unsigned int*)w;

  pack_mask_k<<<dim3(NX / 16, NX), 256, 0, stream>>>(mask, mp);
  tr_cplx_k<<<dim3(NX / 16, NX), 256, 0, stream>>>(kr, ki, kT);
  tr_cplx_cxy_k<<<dim3(NX / 16, NX), 256, 0, stream>>>(sr, si, sT);
  tr_flow_k<<<dim3(NX / 32, NX), 256, 0, stream>>>(fl, fs);
  hipMemsetAsync(out_f, 0, of_b, stream);

  for (int c0 = 0; c0 < NC; c0 += G) {
    pass1_k<<<dim3(NX, G), 256, 0, stream>>>(kT, mp, tmp, c0);
    pass2_k<<<dim3(NX / 8, NT), 512, 0, stream>>>(tmp, sT, im_aux, c0, G,
                                                  c0 == 0 ? 1 : 0);
  }
  scatter_k<<<dim3(NX / BR, NSEG, NT), 1024, 0, stream>>>(im_aux, fs, out_p,
                                                          out_f, NSEG);
  reduce_k<<<200, 256, 0, stream>>>(out_p, out_f, out, NSEG * NT);
}